// Round 9
// baseline (309.064 us; speedup 1.0000x reference)
//
#include <hip/hip_runtime.h>
#include <hip/hip_bf16.h>

// ---------------------------------------------------------------------------
// OptimizedAttention R12: 4-dispatch pipeline; 2-phase K-tile GEMMs.
// R11 post-mortem: per-phase overhead model -- qkv 8-phase: 1425 cyc/phase
// wall vs 620 cyc MFMA work => ~805 cyc FIXED overhead per phase (m201 ref
// ~207). Fix: amortize via bigger phases. Both GEMMs now 2 phases/K-tile:
//   qkv (256x256): ph0 {read B + A-half0; issue A(t+1)[4]} / ph1 {read
//     A-half1; issue B(t+2)[4] -> live buf's dead B region}. Ledger: entry
//     {B(t+1)[4]}; ONE vmcnt(4) per K-tile at ph1 end (lands B(t+1)+A(t+1));
//     prologue 12 issues + vmcnt(4); peels vmcnt(0) then none.
//   outproj NEW 128x256 tile, grid 256 = all CUs, same scheme (A 2 loads,
//     B 4): entry {B(t+1)[4]}, vmcnt(4)/tile; LDS 96 KiB.
// 4 barriers/K-tile (was 8), 1 vmcnt (was 2). attn = R7 (best measured);
// prep = R10. Chunk-XOR LDS swizzle + setprio retained.
// B=2 S=2048 H=2048 NH=32 NKV=8 DH=64 N_REP=4 THETA=1e4
// ---------------------------------------------------------------------------

using bf16 = __hip_bfloat16;
typedef __attribute__((ext_vector_type(8))) __bf16 bf8v;   // MFMA A/B frag (4 VGPR)
typedef __attribute__((ext_vector_type(4))) float  f4v;    // MFMA C/D frag

#define AS1 __attribute__((address_space(1)))
#define AS3 __attribute__((address_space(3)))

constexpr int cB = 2, cS = 2048, cH = 2048, cNH = 32, cNKV = 8, cDH = 64;
constexpr int cQKVW = 3072;   // fused QKV row width (2048 Q + 512 K + 512 V)

template <int N> struct ic { static constexpr int value = N; };

__device__ __forceinline__ void async_cp16(const bf16* g, bf16* l) {
    __builtin_amdgcn_global_load_lds((const AS1 unsigned int*)(const void*)g,
                                     (AS3 unsigned int*)(void*)l, 16, 0, 0);
}

__device__ __forceinline__ f4v mfma_16x16x32(bf8v a, bf8v b, f4v c) {
    return __builtin_amdgcn_mfma_f32_16x16x32_bf16(a, b, c, 0, 0, 0);
}

// ---------------------------------------------------------------------------
// prep: fused  hs->bf16 cvt  +  4 weight transposes (f32 [R][C] -> bf16 [C][R])
// ---------------------------------------------------------------------------
__global__ void prep_kernel(const float* __restrict__ hs, bf16* __restrict__ hsb,
                            const float* __restrict__ Wq, const float* __restrict__ Wk,
                            const float* __restrict__ Wv, const float* __restrict__ Wo,
                            bf16* __restrict__ WT, bf16* __restrict__ WoT) {
    __shared__ float tile[32][33];
    const int bz = blockIdx.x, tid = threadIdx.x;
    if (bz < 8192) {
        int i = bz * 256 + tid;
        float4 v = ((const float4*)hs)[i];
        union { bf16 h[4]; uint2 u; } p;
        p.h[0] = __float2bfloat16(v.x);
        p.h[1] = __float2bfloat16(v.y);
        p.h[2] = __float2bfloat16(v.z);
        p.h[3] = __float2bfloat16(v.w);
        ((uint2*)hsb)[i] = p.u;
        return;
    }
    const int t = bz - 8192;
    const float* in; bf16* outp; int C, x, y;
    if (t < 4096)      { in = Wq; outp = WT;               C = 2048; x = t & 63; y = t >> 6; }
    else if (t < 5120) { int l = t - 4096; in = Wk; outp = WT + 2048 * 2048; C = 512; x = l & 15; y = l >> 4; }
    else if (t < 6144) { int l = t - 5120; in = Wv; outp = WT + 2560 * 2048; C = 512; x = l & 15; y = l >> 4; }
    else               { int l = t - 6144; in = Wo; outp = WoT;             C = 2048; x = l & 63; y = l >> 6; }
    const int c0 = x * 32, r0 = y * 32;
    const int tx = tid & 31, ty = tid >> 5;
    for (int i = ty; i < 32; i += 8)
        tile[i][tx] = in[(long)(r0 + i) * C + c0 + tx];
    __syncthreads();
    for (int i = ty; i < 32; i += 8)
        outp[(long)(c0 + i) * 2048 + r0 + tx] = __float2bfloat16(tile[tx][i]);
}

// ---------------------------------------------------------------------------
// QKV GEMM: 256x256 tile, 2 phases/K-tile (32 MFMA each), 8 waves (2M x 4N).
// Grid 192 1-D, XCD-chunked swizzle. Epilogue: byv 0..7 = Q (plain), 8..9 =
// K (fused RoPE: pairs (d,d+32) lane-local acc[mi][n]<->acc[mi][n+2]),
// 10..11 = V (transposed store to VT[b][kv][d][tok]).
// ---------------------------------------------------------------------------
__global__ __launch_bounds__(512)
void gemm2_qkv(const bf16* __restrict__ A, const bf16* __restrict__ BT,
               bf16* __restrict__ C, const int* __restrict__ pos,
               bf16* __restrict__ VTout, int M, int N, int K) {
    __shared__ __align__(16) bf16 Al[2][256 * 64];   // 32 KB x2
    __shared__ __align__(16) bf16 Bl[2][256 * 64];   // 32 KB x2
    const int tid  = threadIdx.x;
    const int lane = tid & 63, wave = tid >> 6;
    const int wm = wave >> 2, wn = wave & 3;
    const int lm = lane & 15, lq = lane >> 4;
    const int bid = blockIdx.x;
    const int lin = (bid & 7) * 24 + (bid >> 3);
    const int bxv = lin / 12, byv = lin % 12;
    const int bm = bxv * 256, bn = byv * 256;
    const int NT = K >> 6;

    f4v acc[8][4];
    #pragma unroll
    for (int i = 0; i < 8; ++i)
        #pragma unroll
        for (int j = 0; j < 4; ++j)
            for (int r = 0; r < 4; ++r) acc[i][j][r] = 0.f;

    // staging: 256 rows x 8 chunks = 4 loads/thread each for A and B;
    // source chunk XOR-swizzled by row, LDS dest linear.
    const bf16* aP[4]; const bf16* bP[4]; int sD[4];
    #pragma unroll
    for (int i = 0; i < 4; ++i) {
        int g = tid + i * 512;
        int ur = g >> 3, dc = g & 7;
        int gch = dc ^ (ur & 7);
        aP[i] = A  + (long)(bm + ur) * K + gch * 8;
        bP[i] = BT + (long)(bn + ur) * K + gch * 8;
        sD[i] = ur * 64 + dc * 8;
    }
    auto stageA = [&](int buf, int t) {
        long ko = (long)t * 64;
        #pragma unroll
        for (int i = 0; i < 4; ++i) async_cp16(aP[i] + ko, &Al[buf][sD[i]]);
    };
    auto stageB = [&](int buf, int t) {
        long ko = (long)t * 64;
        #pragma unroll
        for (int i = 0; i < 4; ++i) async_cp16(bP[i] + ko, &Bl[buf][sD[i]]);
    };

    const int x7 = lm & 7;
    const int co0 = (lq ^ x7) * 8;
    const int co1 = ((4 + lq) ^ x7) * 8;
    const int abase = (wm * 128 + lm) * 64;
    const int bbase = (wn * 64 + lm) * 64;

    // prologue: B(0)[4], A(0)[4], B(1)[4]; land B(0)+A(0) -> {B(1)[4]} left
    stageB(0, 0); stageA(0, 0); stageB(1, 1);
    asm volatile("s_waitcnt vmcnt(4)" ::: "memory");
    asm volatile("s_barrier" ::: "memory");

    // steady K-tile: entry invariant outstanding = {B(t+1)[4]}
    auto ktile = [&](int t, bool ia, bool ib, auto w) {
        const int cb = t & 1;
        const bf16* Ac = &Al[cb][0];
        const bf16* Bc = &Bl[cb][0];
        // ---- ph0: B frags + A half 0 ----
        bf8v bfr[4][2], afr[4][2];
        #pragma unroll
        for (int n = 0; n < 4; ++n) {
            bfr[n][0] = *(const bf8v*)&Bc[bbase + n * 1024 + co0];
            bfr[n][1] = *(const bf8v*)&Bc[bbase + n * 1024 + co1];
        }
        #pragma unroll
        for (int mi = 0; mi < 4; ++mi) {
            afr[mi][0] = *(const bf8v*)&Ac[abase + mi * 1024 + co0];
            afr[mi][1] = *(const bf8v*)&Ac[abase + mi * 1024 + co1];
        }
        if (ia) stageA(cb ^ 1, t + 1);
        asm volatile("s_barrier" ::: "memory");
        asm volatile("s_waitcnt lgkmcnt(0)" ::: "memory");
        __builtin_amdgcn_s_setprio(1);
        #pragma unroll
        for (int mi = 0; mi < 4; ++mi)
            #pragma unroll
            for (int n = 0; n < 4; ++n) {
                acc[mi][n] = mfma_16x16x32(afr[mi][0], bfr[n][0], acc[mi][n]);
                acc[mi][n] = mfma_16x16x32(afr[mi][1], bfr[n][1], acc[mi][n]);
            }
        __builtin_amdgcn_s_setprio(0);
        asm volatile("s_barrier" ::: "memory");
        // ---- ph1: A half 1 ----
        #pragma unroll
        for (int mi = 0; mi < 4; ++mi) {
            afr[mi][0] = *(const bf8v*)&Ac[abase + (4 + mi) * 1024 + co0];
            afr[mi][1] = *(const bf8v*)&Ac[abase + (4 + mi) * 1024 + co1];
        }
        if (ib) stageB(cb, t + 2);   // live buf's B region is dead after ph0
        asm volatile("s_barrier" ::: "memory");
        asm volatile("s_waitcnt lgkmcnt(0)" ::: "memory");
        __builtin_amdgcn_s_setprio(1);
        #pragma unroll
        for (int mi = 0; mi < 4; ++mi)
            #pragma unroll
            for (int n = 0; n < 4; ++n) {
                acc[4 + mi][n] = mfma_16x16x32(afr[mi][0], bfr[n][0], acc[4 + mi][n]);
                acc[4 + mi][n] = mfma_16x16x32(afr[mi][1], bfr[n][1], acc[4 + mi][n]);
            }
        __builtin_amdgcn_s_setprio(0);
        if constexpr (decltype(w)::value == 4)
            asm volatile("s_waitcnt vmcnt(4)" ::: "memory");  // lands B(t+1)+A(t+1)
        else if constexpr (decltype(w)::value == 0)
            asm volatile("s_waitcnt vmcnt(0)" ::: "memory");  // peel drain
        asm volatile("s_barrier" ::: "memory");
    };

    int t = 0;
    for (; t + 2 < NT; ++t) ktile(t, true, true, ic<4>{});
    ktile(t, true, false, ic<0>{});   // NT-2: no B(NT); drain lands A(NT-1)
    ++t;
    ktile(t, false, false, ic<9>{});  // NT-1: nothing outstanding

    // ---- epilogue ----------------------------------------------------------
    if (byv < 8) {
        #pragma unroll
        for (int mi = 0; mi < 8; ++mi) {
            int row = bm + wm * 128 + mi * 16 + lq * 4;
            #pragma unroll
            for (int n = 0; n < 4; ++n) {
                int col = bn + wn * 64 + n * 16 + lm;
                for (int r = 0; r < 4; ++r)
                    C[(long)(row + r) * N + col] = __float2bfloat16(acc[mi][n][r]);
            }
        }
    } else if (byv < 10) {
        #pragma unroll
        for (int mi = 0; mi < 8; ++mi) {
            int row = bm + wm * 128 + mi * 16 + lq * 4;
            float pr[4];
            for (int r = 0; r < 4; ++r) pr[r] = (float)pos[row + r];
            #pragma unroll
            for (int n = 0; n < 2; ++n) {
                int d = n * 16 + lm;
                float inv = __expf(-(float)(2 * d) * (1.0f / 64.0f) * 9.210340371976184f);
                int col = bn + wn * 64 + n * 16 + lm;
                for (int r = 0; r < 4; ++r) {
                    float a  = acc[mi][n][r];
                    float c2 = acc[mi][n + 2][r];
                    float sn, cs;
                    __sincosf(pr[r] * inv, &sn, &cs);
                    C[(long)(row + r) * N + col]      = __float2bfloat16(a * cs - c2 * sn);
                    C[(long)(row + r) * N + col + 32] = __float2bfloat16(c2 * cs + a * sn);
                }
            }
        }
    } else {
        #pragma unroll
        for (int mi = 0; mi < 8; ++mi) {
            int row = bm + wm * 128 + mi * 16 + lq * 4;
            int b = row >> 11, tok = row & 2047;
            #pragma unroll
            for (int n = 0; n < 4; ++n) {
                int vc = bn + wn * 64 + n * 16 + lm - 2560;
                int kv = vc >> 6, d = vc & 63;
                union { bf16 h4[4]; uint2 v; } pk;
                pk.h4[0] = __float2bfloat16(acc[mi][n][0]);
                pk.h4[1] = __float2bfloat16(acc[mi][n][1]);
                pk.h4[2] = __float2bfloat16(acc[mi][n][2]);
                pk.h4[3] = __float2bfloat16(acc[mi][n][3]);
                *(uint2*)&VTout[((long)(b * 8 + kv) * 64 + d) * 2048 + tok] = pk.v;
            }
        }
    }
}

// ---------------------------------------------------------------------------
// Outproj GEMM: 128x256 tile, 2 phases/K-tile (16 MFMA each), 8 waves
// (2M x 4N, wave tile 64x64, acc[4][4]). Grid 256 = all CUs, XCD-chunked.
// A = 2 loads/thread, B = 4. Ledger: entry {B(t+1)[4]}; ph0 issues A(t+1)
// [2] -> 6; ph1 issues B(t+2)[4] -> 10; vmcnt(4) lands B(t+1)+A(t+1).
// Prologue 10 issues + vmcnt(4). Peels: vmcnt(0), none. LDS 96 KiB.
// ---------------------------------------------------------------------------
__global__ __launch_bounds__(512)
void gemm2_out(const bf16* __restrict__ A, const bf16* __restrict__ BT,
               float* __restrict__ C, int M, int N, int K) {
    __shared__ __align__(16) bf16 Al[2][128 * 64];   // 16 KB x2
    __shared__ __align__(16) bf16 Bl[2][256 * 64];   // 32 KB x2
    const int tid  = threadIdx.x;
    const int lane = tid & 63, wave = tid >> 6;
    const int wm = wave >> 2, wn = wave & 3;
    const int lm = lane & 15, lq = lane >> 4;
    const int bid = blockIdx.x;
    const int lin = (bid & 7) * 32 + (bid >> 3);
    const int bm = (lin >> 3) * 128, bn = (lin & 7) * 256;
    const int NT = K >> 6;

    f4v acc[4][4];
    #pragma unroll
    for (int i = 0; i < 4; ++i)
        #pragma unroll
        for (int j = 0; j < 4; ++j)
            for (int r = 0; r < 4; ++r) acc[i][j][r] = 0.f;

    const bf16* aP[2]; int aD[2];
    #pragma unroll
    for (int i = 0; i < 2; ++i) {
        int g = tid + i * 512;
        int ur = g >> 3, dc = g & 7;
        int gch = dc ^ (ur & 7);
        aP[i] = A + (long)(bm + ur) * K + gch * 8;
        aD[i] = ur * 64 + dc * 8;
    }
    const bf16* bP[4]; int bD[4];
    #pragma unroll
    for (int i = 0; i < 4; ++i) {
        int g = tid + i * 512;
        int ur = g >> 3, dc = g & 7;
        int gch = dc ^ (ur & 7);
        bP[i] = BT + (long)(bn + ur) * K + gch * 8;
        bD[i] = ur * 64 + dc * 8;
    }
    auto stageA = [&](int buf, int t) {
        long ko = (long)t * 64;
        #pragma unroll
        for (int i = 0; i < 2; ++i) async_cp16(aP[i] + ko, &Al[buf][aD[i]]);
    };
    auto stageB = [&](int buf, int t) {
        long ko = (long)t * 64;
        #pragma unroll
        for (int i = 0; i < 4; ++i) async_cp16(bP[i] + ko, &Bl[buf][bD[i]]);
    };

    const int x7 = lm & 7;
    const int co0 = (lq ^ x7) * 8;
    const int co1 = ((4 + lq) ^ x7) * 8;
    const int abase = (wm * 64 + lm) * 64;
    const int bbase = (wn * 64 + lm) * 64;

    // prologue: B(0)[4], A(0)[2], B(1)[4]; land B(0)+A(0) -> {B(1)[4]} left
    stageB(0, 0); stageA(0, 0); stageB(1, 1);
    asm volatile("s_waitcnt vmcnt(4)" ::: "memory");
    asm volatile("s_barrier" ::: "memory");

    auto ktile = [&](int t, bool ia, bool ib, auto w) {
        const int cb = t & 1;
        const bf16* Ac = &Al[cb][0];
        const bf16* Bc = &Bl[cb][0];
        // ---- ph0: B frags + A mi 0,1 ----
        bf8v bfr[4][2], afr[2][2];
        #pragma unroll
        for (int n = 0; n < 4; ++n) {
            bfr[n][0] = *(const bf8v*)&Bc[bbase + n * 1024 + co0];
            bfr[n][1] = *(const bf8v*)&Bc[bbase + n * 1024 + co1];
        }
        #pragma unroll
        for (int mi = 0; mi < 2; ++mi) {
            afr[mi][0] = *(const bf8v*)&Ac[abase + mi * 1024 + co0];
            afr[mi][1] = *(const bf8v*)&Ac[abase + mi * 1024 + co1];
        }
        if (ia) stageA(cb ^ 1, t + 1);
        asm volatile("s_barrier" ::: "memory");
        asm volatile("s_waitcnt lgkmcnt(0)" ::: "memory");
        __builtin_amdgcn_s_setprio(1);
        #pragma unroll
        for (int mi = 0; mi < 2; ++mi)
            #pragma unroll
            for (int n = 0; n < 4; ++n) {
                acc[mi][n] = mfma_16x16x32(afr[mi][0], bfr[n][0], acc[mi][n]);
                acc[mi][n] = mfma_16x16x32(afr[mi][1], bfr[n][1], acc[mi][n]);
            }
        __builtin_amdgcn_s_setprio(0);
        asm volatile("s_barrier" ::: "memory");
        // ---- ph1: A mi 2,3 ----
        #pragma unroll
        for (int mi = 0; mi < 2; ++mi) {
            afr[mi][0] = *(const bf8v*)&Ac[abase + (2 + mi) * 1024 + co0];
            afr[mi][1] = *(const bf8v*)&Ac[abase + (2 + mi) * 1024 + co1];
        }
        if (ib) stageB(cb, t + 2);   // dead B region of live buffer
        asm volatile("s_barrier" ::: "memory");
        asm volatile("s_waitcnt lgkmcnt(0)" ::: "memory");
        __builtin_amdgcn_s_setprio(1);
        #pragma unroll
        for (int mi = 0; mi < 2; ++mi)
            #pragma unroll
            for (int n = 0; n < 4; ++n) {
                acc[2 + mi][n] = mfma_16x16x32(afr[mi][0], bfr[n][0], acc[2 + mi][n]);
                acc[2 + mi][n] = mfma_16x16x32(afr[mi][1], bfr[n][1], acc[2 + mi][n]);
            }
        __builtin_amdgcn_s_setprio(0);
        if constexpr (decltype(w)::value == 4)
            asm volatile("s_waitcnt vmcnt(4)" ::: "memory");
        else if constexpr (decltype(w)::value == 0)
            asm volatile("s_waitcnt vmcnt(0)" ::: "memory");
        asm volatile("s_barrier" ::: "memory");
    };

    int t = 0;
    for (; t + 2 < NT; ++t) ktile(t, true, true, ic<4>{});
    ktile(t, true, false, ic<0>{});
    ++t;
    ktile(t, false, false, ic<9>{});

    #pragma unroll
    for (int mi = 0; mi < 4; ++mi) {
        int row = bm + wm * 64 + mi * 16 + lq * 4;
        #pragma unroll
        for (int n = 0; n < 4; ++n) {
            int col = bn + wn * 64 + n * 16 + lm;
            for (int r = 0; r < 4; ++r)
                C[(long)(row + r) * N + col] = acc[mi][n][r];
        }
    }
}

// ---------------------------------------------------------------------------
// Causal GQA flash attention (R7 verbatim -- best measured). 512 blocks;
// paired q-tiles (15-p, p) = uniform 34 steps; 4 waves x 32q; XOR-swizzled
// async K/VT staging, dbuf, s_barrier+vmcnt(4); fixed-base exp2 softmax;
// Q-RoPE fused; setprio around MFMA. XCD affinity: idx&7 = kvh.
// ---------------------------------------------------------------------------
__global__ __launch_bounds__(256)
void attn_kernel(const bf16* __restrict__ QKV, const bf16* __restrict__ VT,
                 const int* __restrict__ pos, bf16* __restrict__ O) {
    __shared__ __align__(16) bf16 Kl[2][64 * 64];   // [buf][key][dh]   8KB x2
    __shared__ __align__(16) bf16 Vl[2][64 * 64];   // [buf][d][key]    8KB x2
    __shared__ __align__(16) bf16 Pl[4][16 * 64];   // per-wave P tile  2KB x4
    const int tid  = threadIdx.x;
    const int wave = tid >> 6, lane = tid & 63;
    const int lm = lane & 15, lq = lane >> 4;
    const int idx = blockIdx.x;
    const int pair = idx >> 6;                      // 0..7
    const int bh2 = idx & 15;
    const int rep = (idx >> 4) & 3;
    const int b = bh2 >> 3, kvh = bh2 & 7;
    const int h = kvh * 4 + rep;

    constexpr float SCALE = 0.18033688011112042f;

    bf16* pw = &Pl[wave][0];
    const int x7 = lm & 7;
    int wr_addr[4], rd_addr[2];
    for (int t = 0; t < 4; ++t)
        wr_addr[t] = lm * 64 + (((t * 2 + (lq >> 1)) ^ x7) * 8) + (lq & 1) * 4;
    for (int c = 0; c < 2; ++c)
        rd_addr[c] = lm * 64 + (((c * 4 + lq) ^ x7) * 8);

    const int srow = tid >> 3, sch = tid & 7;
    const bf16* kgb = QKV + (long)b * cS * cQKVW + 2048 + kvh * cDH;
    const bf16* vgb = VT + (long)(b * cNKV + kvh) * cDH * cS;
    const int sc8 = (sch ^ (srow & 7)) * 8;    // (32+srow)&7 == srow&7
    const bf16* kp0 = kgb + (long)srow * cQKVW + sc8;
    const bf16* kp1 = kgb + (long)(32 + srow) * cQKVW + sc8;
    const bf16* vp0 = vgb + (long)srow * cS + sc8;
    const bf16* vp1 = vgb + (long)(32 + srow) * cS + sc8;
    auto stage = [&](int buf, int j0) {
        long ko = (long)j0 * cQKVW;
        async_cp16(kp0 + ko, &Kl[buf][tid * 8]);
        async_cp16(kp1 + ko, &Kl[buf][2048 + tid * 8]);
        async_cp16(vp0 + j0, &Vl[buf][tid * 8]);
        async_cp16(vp1 + j0, &Vl[buf][2048 + tid * 8]);
    };

    for (int pass = 0; pass < 2; ++pass) {
        const int qblk = pass ? pair : 15 - pair;   // heavy pass first
        const int q0 = qblk * 128;
        const int qw = q0 + wave * 32;              // this wave's 32 queries
        const int nsteps = 2 * qblk + 2;

        bf8v qf[2][2];
        for (int u = 0; u < 2; ++u) {
            const int qi = qw + u * 16 + lm;
            const bf16* qrow = QKV + (long)(b * cS + qi) * cQKVW + h * cDH;
            float p = (float)pos[b * cS + qi];
            bf8v r0 = *(const bf8v*)(qrow + lq * 8);
            bf8v r1 = *(const bf8v*)(qrow + 32 + lq * 8);
            bf8v t0, t1;
            for (int j = 0; j < 8; ++j) {
                int d = lq * 8 + j;
                float inv = __expf(-(float)(2 * d) * (1.0f / 64.0f) * 9.210340371976184f);
                float sn, cs;
                __sincosf(p * inv, &sn, &cs);
                float a = (float)r0[j], c2 = (float)r1[j];
                t0[j] = (__bf16)((a * cs - c2 * sn) * SCALE);
                t1[j] = (__bf16)((c2 * cs + a * sn) * SCALE);
            }
            qf[u][0] = t0; qf[u][1] = t1;
        }

        float lrow[2] = {0.f, 0.f};
        f4v o[2][4];
        for (int u = 0; u < 2; ++u)
            for (int t = 0; t < 4; ++t)
                for (int r = 0; r < 4; ++r) o[u][t][r] = 0.f;

        stage(0, 0);
        for (int step = 0; step < nsteps; ++step) {
            const int j0 = step * 64;
            const int cur = step & 1;
            if (step + 1 < nsteps) {
                stage(cur ^ 1, j0 + 64);
                asm volatile("s_waitcnt vmcnt(4)" ::: "memory");  // current tile only
            } else {
                asm volatile("s_waitcnt vmcnt(0)" ::: "memory");
            }
            asm volatile("s_barrier" ::: "memory");

            if (qw + 31 >= j0) {   // wave-uniform; skip fully-masked steps
                f4v st[2][4];
                for (int u = 0; u < 2; ++u)
                    for (int t = 0; t < 4; ++t)
                        for (int r = 0; r < 4; ++r) st[u][t][r] = 0.f;
                __builtin_amdgcn_s_setprio(1);
                for (int t = 0; t < 4; ++t) {
                    int kr = t * 16 + lm;
                    bf8v kf0 = *(const bf8v*)&Kl[cur][kr * 64 + ((lq ^ (kr & 7)) * 8)];
                    bf8v kf1 = *(const bf8v*)&Kl[cur][kr * 64 + (((4 + lq) ^ (kr & 7)) * 8)];
                    for (int u = 0; u < 2; ++u) {
                        st[u][t] = mfma_16x16x32(kf0, qf[u][0], st[u][t]);
                        st[u][t] = mfma_16x16x32(kf1, qf[u][1], st[u][t]);
                    }
                }
                __builtin_amdgcn_s_setprio(0);
                bf8v vf[4][2];
                for (int t = 0; t < 4; ++t) {
                    int vr = t * 16 + lm;
                    vf[t][0] = *(const bf8v*)&Vl[cur][vr * 64 + ((lq ^ (vr & 7)) * 8)];
                    vf[t][1] = *(const bf8v*)&Vl[cur][vr * 64 + (((4 + lq) ^ (vr & 7)) * 8)];
                }
                const bool full = (j0 + 63 <= qw);
                for (int u = 0; u < 2; ++u) {
                    float part = 0.f;
                    if (full) {
                        for (int t = 0; t < 4; ++t)
                            for (int r = 0; r < 4; ++r) {
                                float pv = __builtin_amdgcn_exp2f(st[u][t][r]);
                                st[u][t][r] = pv;
                                part += pv;
                            }
                    } else {
                        const int qi = qw + u * 16 + lm;
                        for (int t = 0; t < 4; ++t)
                            for (int r = 0; r < 4; ++r) {
                                int key = j0 + t * 16 + lq * 4 + r;
                                float pv = (key <= qi)
                                         ? __builtin_amdgcn_exp2f(st[u][t][r]) : 0.f;
                                st[u][t][r] = pv;
                                part += pv;
                            }
                    }
                    lrow[u] += part;
                    for (int t = 0; t < 4; ++t) {
                        union { bf16 h4[4]; uint2 v; } pk;
                        pk.h4[0] = __float2bfloat16(st[u][t][0]);
                        pk.h4[1] = __float2bfloat16(st[u][t][1]);
                        pk.h4[2] = __float2bfloat16(st[u][t][2]);
                        pk.h4[3] = __float2bfloat16(st[u][t][3]);
                        *(uint2*)&pw[wr_addr[t]] = pk.v;
                    }
                    asm volatile("s_waitcnt lgkmcnt(0)" ::: "memory");
                    bf8v pb0 = *(const bf8v*)&pw[rd_addr[0]];
                    bf8v pb1 = *(const bf8v*)&pw[rd_addr[1]];
                    __builtin_amdgcn_s_setprio(1);
                    for (int t = 0; t < 4; ++t) {
                        o[u][t] = mfma_16x16x32(vf[t][0], pb0, o[u][t]);
                        o[u][t] = mfma_16x16x32(vf[t][1], pb1, o[u][t]);
                    }
                    __builtin_amdgcn_s_setprio(0);
                }
            }
            asm volatile("s_barrier" ::: "memory");   // reads done -> next stage may overwrite
        }

        for (int u = 0; u < 2; ++u) {
            lrow[u] += __shfl_xor(lrow[u], 16);
            lrow[u] += __shfl_xor(lrow[u], 32);
            float inv = 1.0f / lrow[u];
            const int qi = qw + u * 16 + lm;
            bf16* orow = O + ((long)(b * cS + qi) * cNH + h) * cDH;
            for (int t = 0; t < 4; ++t) {
                union { bf16 h4[4]; uint2 v; } pk;
                pk.h4[0] = __float2bfloat16(o[u][t][0] * inv);
                pk.h4[1] = __float2bfloat16(o[u][t][1] * inv);
                pk.h4[2] = __float2bfloat16(o[u][t][2] * inv);
                pk.h4[3] = __float2bfloat16(o[u][t][3] * inv);
                *(uint2*)(orow + t * 16 + lq * 4) = pk.v;
            }
        }
    }
}

// ---------------------------------------------------------------------------
// launcher: 4 dispatches
// ---------------------------------------------------------------------------
extern "C" void kernel_launch(void* const* d_in, const int* in_sizes, int n_in,
                              void* d_out, int out_size, void* d_ws, size_t ws_size,
                              hipStream_t stream) {
    const float* hs  = (const float*)d_in[0];
    const int*   pos = (const int*)d_in[1];
    const float* Wq  = (const float*)d_in[2];
    const float* Wk  = (const float*)d_in[3];
    const float* Wv  = (const float*)d_in[4];
    const float* Wo  = (const float*)d_in[5];
    float* out = (float*)d_out;
    char* ws = (char*)d_ws;

    // workspace layout (bytes)
    bf16* hsb = (bf16*)(ws + 0);              // [4096][2048]        16.78 MB
    bf16* WT  = (bf16*)(ws + 16777216);       // [3072][2048] fused QKV^T 12.58 MB
    bf16* WoT = (bf16*)(ws + 29360128);       // [2048][2048]         8.39 MB
    bf16* QKV = (bf16*)(ws + 37748736);       // [4096][3072]        25.17 MB
    bf16* VTb = (bf16*)(ws + 62914560);       // [2][8][64][2048]     4.19 MB
    bf16* AOb = (bf16*)(ws + 67108864);       // [4096][2048]        16.78 MB
    // total 83.9 MB

    // 1) fused prep: hs->bf16 + all weight transposes
    prep_kernel<<<18432, 256, 0, stream>>>(hs, hsb, Wq, Wk, Wv, Wo, WT, WoT);
    // 2) fused QKV projection + K-RoPE + V-transpose (2-phase 256^2, XCD swz)
    gemm2_qkv<<<192, 512, 0, stream>>>(hsb, WT, QKV, pos, VTb,
                                       4096, cQKVW, 2048);
    // 3) attention (R7: 512 uniform blocks, paired q-tiles, XCD affinity)
    attn_kernel<<<512, 256, 0, stream>>>(QKV, VTb, pos, AOb);
    // 4) output projection -> fp32 d_out (2-phase 128x256, 256 blocks, XCD swz)
    gemm2_out<<<256, 512, 0, stream>>>(AOb, WoT, out, 4096, 2048, 2048);
}

// Round 10
// 304.702 us; speedup vs baseline: 1.0143x; 1.0143x over previous
//
#include <hip/hip_runtime.h>
#include <hip/hip_bf16.h>

// ---------------------------------------------------------------------------
// OptimizedAttention R13: best-of-measured composite + attn P-drain merge.
// R12 post-mortem: phase overhead is PROPORTIONAL (LDS-read serialized with
// MFMA under lockstep barriers), not fixed. Differencing R11/R12: both GEMMs
// prefer ~16-MFMA phases -> qkv keeps R11's 8-phase (76.0us), outproj keeps
// R12's 2-phase 128x256 (16-MFMA phases).
// New: attn per-step P roundtrip restructured -- per-u P buffers, softmax+
// pack+write both u, ONE lgkmcnt(0) drain (was two), read+PV both; RoPE
// inv-freq table hoisted out of the pass loop.
// B=2 S=2048 H=2048 NH=32 NKV=8 DH=64 N_REP=4 THETA=1e4
// ---------------------------------------------------------------------------

using bf16 = __hip_bfloat16;
typedef __attribute__((ext_vector_type(8))) __bf16 bf8v;   // MFMA A/B frag (4 VGPR)
typedef __attribute__((ext_vector_type(4))) float  f4v;    // MFMA C/D frag

#define AS1 __attribute__((address_space(1)))
#define AS3 __attribute__((address_space(3)))

constexpr int cB = 2, cS = 2048, cH = 2048, cNH = 32, cNKV = 8, cDH = 64;
constexpr int cQKVW = 3072;   // fused QKV row width (2048 Q + 512 K + 512 V)

template <int N> struct ic { static constexpr int value = N; };

__device__ __forceinline__ void async_cp16(const bf16* g, bf16* l) {
    __builtin_amdgcn_global_load_lds((const AS1 unsigned int*)(const void*)g,
                                     (AS3 unsigned int*)(void*)l, 16, 0, 0);
}

__device__ __forceinline__ f4v mfma_16x16x32(bf8v a, bf8v b, f4v c) {
    return __builtin_amdgcn_mfma_f32_16x16x32_bf16(a, b, c, 0, 0, 0);
}

// ---------------------------------------------------------------------------
// prep: fused  hs->bf16 cvt  +  4 weight transposes (f32 [R][C] -> bf16 [C][R])
// ---------------------------------------------------------------------------
__global__ void prep_kernel(const float* __restrict__ hs, bf16* __restrict__ hsb,
                            const float* __restrict__ Wq, const float* __restrict__ Wk,
                            const float* __restrict__ Wv, const float* __restrict__ Wo,
                            bf16* __restrict__ WT, bf16* __restrict__ WoT) {
    __shared__ float tile[32][33];
    const int bz = blockIdx.x, tid = threadIdx.x;
    if (bz < 8192) {
        int i = bz * 256 + tid;
        float4 v = ((const float4*)hs)[i];
        union { bf16 h[4]; uint2 u; } p;
        p.h[0] = __float2bfloat16(v.x);
        p.h[1] = __float2bfloat16(v.y);
        p.h[2] = __float2bfloat16(v.z);
        p.h[3] = __float2bfloat16(v.w);
        ((uint2*)hsb)[i] = p.u;
        return;
    }
    const int t = bz - 8192;
    const float* in; bf16* outp; int C, x, y;
    if (t < 4096)      { in = Wq; outp = WT;               C = 2048; x = t & 63; y = t >> 6; }
    else if (t < 5120) { int l = t - 4096; in = Wk; outp = WT + 2048 * 2048; C = 512; x = l & 15; y = l >> 4; }
    else if (t < 6144) { int l = t - 5120; in = Wv; outp = WT + 2560 * 2048; C = 512; x = l & 15; y = l >> 4; }
    else               { int l = t - 6144; in = Wo; outp = WoT;             C = 2048; x = l & 63; y = l >> 6; }
    const int c0 = x * 32, r0 = y * 32;
    const int tx = tid & 31, ty = tid >> 5;
    for (int i = ty; i < 32; i += 8)
        tile[i][tx] = in[(long)(r0 + i) * C + c0 + tx];
    __syncthreads();
    for (int i = ty; i < 32; i += 8)
        outp[(long)(c0 + i) * 2048 + r0 + tx] = __float2bfloat16(tile[tx][i]);
}

// ---------------------------------------------------------------------------
// 256x256-tile 8-phase GEMM core (R6/R11-verified ledger).
// Per K-tile t (4 phases of {ds_read; prefetch-issue; barrier; lgkmcnt(0);
// setprio(1); 16 MFMA; setprio(0); [counted vmcnt]; barrier}):
//   ph0: issue A-u0(t+1)->buf^1   ph1: issue A-u1(t+1)->buf^1, vmcnt(8)
//   ph2: issue B-h0(t+2)->buf     ph3: issue B-h1(t+2)->buf,   vmcnt(6)
// B region of buf is dead after ph0; entry ledger {A-u1(t)[2], B(t+1)[4]}=6.
// Chunk-XOR swizzle c^=(row&7) on global SOURCE + ds_read (conflict-free).
// ---------------------------------------------------------------------------
#define GEMM_CORE(AARG, BTARG, KARG, BXV, BYV)                                  \
    __shared__ __align__(16) bf16 Al[2][256 * 64];                              \
    __shared__ __align__(16) bf16 Bl[2][256 * 64];                              \
    const int tid  = threadIdx.x;                                               \
    const int lane = tid & 63;                                                  \
    const int wave = tid >> 6;                                                  \
    const int wm = wave >> 2, wn = wave & 3;                                    \
    const int lm = lane & 15, lq = lane >> 4;                                   \
    const int bm = (BXV) * 256, bn = (BYV) * 256;                               \
    const int NT = (KARG) >> 6;                                                 \
    f4v acc[8][4];                                                              \
    _Pragma("unroll")                                                           \
    for (int i = 0; i < 8; ++i)                                                 \
        _Pragma("unroll")                                                       \
        for (int j = 0; j < 4; ++j)                                             \
            for (int r = 0; r < 4; ++r) acc[i][j][r] = 0.f;                     \
    const bf16* aP[2][2]; const bf16* bP[2][2];                                 \
    int aD[2][2], bD[2][2];                                                     \
    _Pragma("unroll")                                                           \
    for (int u = 0; u < 2; ++u)                                                 \
        _Pragma("unroll")                                                       \
        for (int i = 0; i < 2; ++i) {                                           \
            int g = tid + i * 512;                                              \
            int ur = g >> 3, dc = g & 7;                                        \
            int row = ur + (ur & 64) + u * 64;                                  \
            int gch = dc ^ (row & 7);                                           \
            aP[u][i] = (AARG) + (long)(bm + row) * (KARG) + gch * 8;            \
            aD[u][i] = row * 64 + dc * 8;                                       \
        }                                                                       \
    _Pragma("unroll")                                                           \
    for (int h = 0; h < 2; ++h)                                                 \
        _Pragma("unroll")                                                       \
        for (int i = 0; i < 2; ++i) {                                           \
            int g = tid + i * 512;                                              \
            int ur = g >> 3, dc = g & 7;                                        \
            int row = h * 128 + ur;                                             \
            int gch = dc ^ (row & 7);                                           \
            bP[h][i] = (BTARG) + (long)(bn + row) * (KARG) + gch * 8;           \
            bD[h][i] = row * 64 + dc * 8;                                       \
        }                                                                       \
    auto stageA = [&](int buf, int t, int u) {                                  \
        long ko = (long)t * 64;                                                 \
        async_cp16(aP[u][0] + ko, &Al[buf][aD[u][0]]);                          \
        async_cp16(aP[u][1] + ko, &Al[buf][aD[u][1]]);                          \
    };                                                                          \
    auto stageB = [&](int buf, int t, int h) {                                  \
        long ko = (long)t * 64;                                                 \
        async_cp16(bP[h][0] + ko, &Bl[buf][bD[h][0]]);                          \
        async_cp16(bP[h][1] + ko, &Bl[buf][bD[h][1]]);                          \
    };                                                                          \
    const int x7 = lm & 7;                                                      \
    const int co0 = (lq ^ x7) * 8;                                              \
    const int co1 = ((4 + lq) ^ x7) * 8;                                        \
    const int abase = (wm * 128 + lm) * 64;                                     \
    const int bbase = (wn * 64 + lm) * 64;                                      \
    stageB(0, 0, 0); stageB(0, 0, 1); stageA(0, 0, 0); stageA(0, 0, 1);         \
    stageB(1, 1, 0); stageB(1, 1, 1);                                           \
    asm volatile("s_waitcnt vmcnt(6)" ::: "memory");                            \
    asm volatile("s_barrier" ::: "memory");                                     \
    auto ktile = [&](int t, bool ia, bool ib, auto w1, auto w3) {               \
        const int cb = t & 1;                                                   \
        const bf16* Ac = &Al[cb][0];                                            \
        const bf16* Bc = &Bl[cb][0];                                            \
        bf8v bfr[4][2];                                                         \
        _Pragma("unroll")                                                       \
        for (int q = 0; q < 4; ++q) {                                           \
            bf8v afr[2][2];                                                     \
            if (q == 0) {                                                       \
                _Pragma("unroll")                                               \
                for (int n = 0; n < 4; ++n) {                                   \
                    bfr[n][0] = *(const bf8v*)&Bc[bbase + n * 1024 + co0];      \
                    bfr[n][1] = *(const bf8v*)&Bc[bbase + n * 1024 + co1];      \
                }                                                               \
            }                                                                   \
            _Pragma("unroll")                                                   \
            for (int i2 = 0; i2 < 2; ++i2) {                                    \
                afr[i2][0] = *(const bf8v*)&Ac[abase + (q * 2 + i2) * 1024 + co0]; \
                afr[i2][1] = *(const bf8v*)&Ac[abase + (q * 2 + i2) * 1024 + co1]; \
            }                                                                   \
            if (q == 0 && ia) stageA(cb ^ 1, t + 1, 0);                         \
            if (q == 1 && ia) stageA(cb ^ 1, t + 1, 1);                         \
            if (q == 2 && ib) stageB(cb, t + 2, 0);                             \
            if (q == 3 && ib) stageB(cb, t + 2, 1);                             \
            asm volatile("s_barrier" ::: "memory");                             \
            asm volatile("s_waitcnt lgkmcnt(0)" ::: "memory");                  \
            __builtin_amdgcn_s_setprio(1);                                      \
            _Pragma("unroll")                                                   \
            for (int i2 = 0; i2 < 2; ++i2)                                      \
                _Pragma("unroll")                                               \
                for (int n = 0; n < 4; ++n) {                                   \
                    acc[q * 2 + i2][n] = mfma_16x16x32(afr[i2][0], bfr[n][0], acc[q * 2 + i2][n]); \
                    acc[q * 2 + i2][n] = mfma_16x16x32(afr[i2][1], bfr[n][1], acc[q * 2 + i2][n]); \
                }                                                               \
            __builtin_amdgcn_s_setprio(0);                                      \
            if (q == 1) {                                                       \
                if constexpr (decltype(w1)::value == 8)                         \
                    asm volatile("s_waitcnt vmcnt(8)" ::: "memory");            \
                else                                                            \
                    asm volatile("s_waitcnt vmcnt(0)" ::: "memory");            \
            }                                                                   \
            if (q == 3) {                                                       \
                if constexpr (decltype(w3)::value == 1)                         \
                    asm volatile("s_waitcnt vmcnt(6)" ::: "memory");            \
                else if constexpr (decltype(w3)::value == 2)                    \
                    asm volatile("s_waitcnt vmcnt(2)" ::: "memory");            \
            }                                                                   \
            asm volatile("s_barrier" ::: "memory");                             \
        }                                                                       \
    };                                                                          \
    {                                                                           \
        int t = 0;                                                              \
        for (; t + 2 < NT; ++t) ktile(t, true, true, ic<8>{}, ic<1>{});         \
        ktile(t, true, false, ic<8>{}, ic<2>{});                                \
        ++t;                                                                    \
        ktile(t, false, false, ic<0>{}, ic<0>{});                               \
    }

// QKV variant (R11 exact): grid 192 1-D, XCD-chunked swizzle. byv 0..7 = Q,
// 8..9 = K (fused RoPE; pairs (d,d+32) lane-local acc[mi][n]<->acc[mi][n+2]),
// 10..11 = V (transposed store to VT[b][kv][d][tok]).
__global__ __launch_bounds__(512)
void gemm_bt8_qkv(const bf16* __restrict__ A, const bf16* __restrict__ BT,
                  bf16* __restrict__ C, const int* __restrict__ pos,
                  bf16* __restrict__ VTout, int M, int N, int K) {
    const int bid = blockIdx.x;
    const int lin = (bid & 7) * 24 + (bid >> 3);
    const int bxv = lin / 12, byv = lin % 12;
    GEMM_CORE(A, BT, K, bxv, byv)
    if (byv < 8) {
        #pragma unroll
        for (int mi = 0; mi < 8; ++mi) {
            int row = bm + wm * 128 + mi * 16 + lq * 4;
            #pragma unroll
            for (int n = 0; n < 4; ++n) {
                int col = bn + wn * 64 + n * 16 + lm;
                for (int r = 0; r < 4; ++r)
                    C[(long)(row + r) * N + col] = __float2bfloat16(acc[mi][n][r]);
            }
        }
    } else if (byv < 10) {
        #pragma unroll
        for (int mi = 0; mi < 8; ++mi) {
            int row = bm + wm * 128 + mi * 16 + lq * 4;
            float pr[4];
            for (int r = 0; r < 4; ++r) pr[r] = (float)pos[row + r];
            #pragma unroll
            for (int n = 0; n < 2; ++n) {
                int d = n * 16 + lm;
                float inv = __expf(-(float)(2 * d) * (1.0f / 64.0f) * 9.210340371976184f);
                int col = bn + wn * 64 + n * 16 + lm;
                for (int r = 0; r < 4; ++r) {
                    float a  = acc[mi][n][r];
                    float c2 = acc[mi][n + 2][r];
                    float sn, cs;
                    __sincosf(pr[r] * inv, &sn, &cs);
                    C[(long)(row + r) * N + col]      = __float2bfloat16(a * cs - c2 * sn);
                    C[(long)(row + r) * N + col + 32] = __float2bfloat16(c2 * cs + a * sn);
                }
            }
        }
    } else {
        #pragma unroll
        for (int mi = 0; mi < 8; ++mi) {
            int row = bm + wm * 128 + mi * 16 + lq * 4;
            int b = row >> 11, tok = row & 2047;
            #pragma unroll
            for (int n = 0; n < 4; ++n) {
                int vc = bn + wn * 64 + n * 16 + lm - 2560;
                int kv = vc >> 6, d = vc & 63;
                union { bf16 h4[4]; uint2 v; } pk;
                pk.h4[0] = __float2bfloat16(acc[mi][n][0]);
                pk.h4[1] = __float2bfloat16(acc[mi][n][1]);
                pk.h4[2] = __float2bfloat16(acc[mi][n][2]);
                pk.h4[3] = __float2bfloat16(acc[mi][n][3]);
                *(uint2*)&VTout[((long)(b * 8 + kv) * 64 + d) * 2048 + tok] = pk.v;
            }
        }
    }
}

// ---------------------------------------------------------------------------
// Outproj GEMM (R12 exact): 128x256 tile, 2 phases/K-tile (16 MFMA each),
// 8 waves (2M x 4N, wave tile 64x64, acc[4][4]). Grid 256 = all CUs, XCD-
// chunked. Ledger: entry {B(t+1)[4]}; ph0 issues A(t+1)[2]; ph1 issues
// B(t+2)[4] into live buf's dead B region; vmcnt(4) lands B(t+1)+A(t+1).
// ---------------------------------------------------------------------------
__global__ __launch_bounds__(512)
void gemm2_out(const bf16* __restrict__ A, const bf16* __restrict__ BT,
               float* __restrict__ C, int M, int N, int K) {
    __shared__ __align__(16) bf16 Al[2][128 * 64];   // 16 KB x2
    __shared__ __align__(16) bf16 Bl[2][256 * 64];   // 32 KB x2
    const int tid  = threadIdx.x;
    const int lane = tid & 63, wave = tid >> 6;
    const int wm = wave >> 2, wn = wave & 3;
    const int lm = lane & 15, lq = lane >> 4;
    const int bid = blockIdx.x;
    const int lin = (bid & 7) * 32 + (bid >> 3);
    const int bm = (lin >> 3) * 128, bn = (lin & 7) * 256;
    const int NT = K >> 6;

    f4v acc[4][4];
    #pragma unroll
    for (int i = 0; i < 4; ++i)
        #pragma unroll
        for (int j = 0; j < 4; ++j)
            for (int r = 0; r < 4; ++r) acc[i][j][r] = 0.f;

    const bf16* aP[2]; int aD[2];
    #pragma unroll
    for (int i = 0; i < 2; ++i) {
        int g = tid + i * 512;
        int ur = g >> 3, dc = g & 7;
        int gch = dc ^ (ur & 7);
        aP[i] = A + (long)(bm + ur) * K + gch * 8;
        aD[i] = ur * 64 + dc * 8;
    }
    const bf16* bP[4]; int bD[4];
    #pragma unroll
    for (int i = 0; i < 4; ++i) {
        int g = tid + i * 512;
        int ur = g >> 3, dc = g & 7;
        int gch = dc ^ (ur & 7);
        bP[i] = BT + (long)(bn + ur) * K + gch * 8;
        bD[i] = ur * 64 + dc * 8;
    }
    auto stageA = [&](int buf, int t) {
        long ko = (long)t * 64;
        #pragma unroll
        for (int i = 0; i < 2; ++i) async_cp16(aP[i] + ko, &Al[buf][aD[i]]);
    };
    auto stageB = [&](int buf, int t) {
        long ko = (long)t * 64;
        #pragma unroll
        for (int i = 0; i < 4; ++i) async_cp16(bP[i] + ko, &Bl[buf][bD[i]]);
    };

    const int x7 = lm & 7;
    const int co0 = (lq ^ x7) * 8;
    const int co1 = ((4 + lq) ^ x7) * 8;
    const int abase = (wm * 64 + lm) * 64;
    const int bbase = (wn * 64 + lm) * 64;

    stageB(0, 0); stageA(0, 0); stageB(1, 1);
    asm volatile("s_waitcnt vmcnt(4)" ::: "memory");
    asm volatile("s_barrier" ::: "memory");

    auto ktile = [&](int t, bool ia, bool ib, auto w) {
        const int cb = t & 1;
        const bf16* Ac = &Al[cb][0];
        const bf16* Bc = &Bl[cb][0];
        bf8v bfr[4][2], afr[2][2];
        #pragma unroll
        for (int n = 0; n < 4; ++n) {
            bfr[n][0] = *(const bf8v*)&Bc[bbase + n * 1024 + co0];
            bfr[n][1] = *(const bf8v*)&Bc[bbase + n * 1024 + co1];
        }
        #pragma unroll
        for (int mi = 0; mi < 2; ++mi) {
            afr[mi][0] = *(const bf8v*)&Ac[abase + mi * 1024 + co0];
            afr[mi][1] = *(const bf8v*)&Ac[abase + mi * 1024 + co1];
        }
        if (ia) stageA(cb ^ 1, t + 1);
        asm volatile("s_barrier" ::: "memory");
        asm volatile("s_waitcnt lgkmcnt(0)" ::: "memory");
        __builtin_amdgcn_s_setprio(1);
        #pragma unroll
        for (int mi = 0; mi < 2; ++mi)
            #pragma unroll
            for (int n = 0; n < 4; ++n) {
                acc[mi][n] = mfma_16x16x32(afr[mi][0], bfr[n][0], acc[mi][n]);
                acc[mi][n] = mfma_16x16x32(afr[mi][1], bfr[n][1], acc[mi][n]);
            }
        __builtin_amdgcn_s_setprio(0);
        asm volatile("s_barrier" ::: "memory");
        #pragma unroll
        for (int mi = 0; mi < 2; ++mi) {
            afr[mi][0] = *(const bf8v*)&Ac[abase + (2 + mi) * 1024 + co0];
            afr[mi][1] = *(const bf8v*)&Ac[abase + (2 + mi) * 1024 + co1];
        }
        if (ib) stageB(cb, t + 2);   // dead B region of live buffer
        asm volatile("s_barrier" ::: "memory");
        asm volatile("s_waitcnt lgkmcnt(0)" ::: "memory");
        __builtin_amdgcn_s_setprio(1);
        #pragma unroll
        for (int mi = 0; mi < 2; ++mi)
            #pragma unroll
            for (int n = 0; n < 4; ++n) {
                acc[2 + mi][n] = mfma_16x16x32(afr[mi][0], bfr[n][0], acc[2 + mi][n]);
                acc[2 + mi][n] = mfma_16x16x32(afr[mi][1], bfr[n][1], acc[2 + mi][n]);
            }
        __builtin_amdgcn_s_setprio(0);
        if constexpr (decltype(w)::value == 4)
            asm volatile("s_waitcnt vmcnt(4)" ::: "memory");
        else if constexpr (decltype(w)::value == 0)
            asm volatile("s_waitcnt vmcnt(0)" ::: "memory");
        asm volatile("s_barrier" ::: "memory");
    };

    int t = 0;
    for (; t + 2 < NT; ++t) ktile(t, true, true, ic<4>{});
    ktile(t, true, false, ic<0>{});
    ++t;
    ktile(t, false, false, ic<9>{});

    #pragma unroll
    for (int mi = 0; mi < 4; ++mi) {
        int row = bm + wm * 64 + mi * 16 + lq * 4;
        #pragma unroll
        for (int n = 0; n < 4; ++n) {
            int col = bn + wn * 64 + n * 16 + lm;
            for (int r = 0; r < 4; ++r)
                C[(long)(row + r) * N + col] = acc[mi][n][r];
        }
    }
}

// ---------------------------------------------------------------------------
// Causal GQA flash attention (R7 structure + merged P-drain). 512 blocks;
// paired q-tiles (15-p, p) = uniform 34 steps; 4 waves x 32q; XOR-swizzled
// async K/VT staging, dbuf, s_barrier+vmcnt(4); fixed-base exp2 softmax;
// Q-RoPE fused (inv-freq table hoisted); setprio around MFMA.
// Per step: QK both u -> softmax+pack+write u0,u1 (separate P buffers) ->
// ONE lgkmcnt(0) -> read+PV u0,u1. XCD affinity: idx&7 = kvh.
// ---------------------------------------------------------------------------
__global__ __launch_bounds__(256)
void attn_kernel(const bf16* __restrict__ QKV, const bf16* __restrict__ VT,
                 const int* __restrict__ pos, bf16* __restrict__ O) {
    __shared__ __align__(16) bf16 Kl[2][64 * 64];      // [buf][key][dh]  8KB x2
    __shared__ __align__(16) bf16 Vl[2][64 * 64];      // [buf][d][key]   8KB x2
    __shared__ __align__(16) bf16 Pl[4][2][16 * 64];   // per-wave, per-u 4KB x4
    const int tid  = threadIdx.x;
    const int wave = tid >> 6, lane = tid & 63;
    const int lm = lane & 15, lq = lane >> 4;
    const int idx = blockIdx.x;
    const int pair = idx >> 6;                      // 0..7
    const int bh2 = idx & 15;
    const int rep = (idx >> 4) & 3;
    const int b = bh2 >> 3, kvh = bh2 & 7;
    const int h = kvh * 4 + rep;

    constexpr float SCALE = 0.18033688011112042f;

    const int x7 = lm & 7;
    int wr_addr[4], rd_addr[2];
    for (int t = 0; t < 4; ++t)
        wr_addr[t] = lm * 64 + (((t * 2 + (lq >> 1)) ^ x7) * 8) + (lq & 1) * 4;
    for (int c = 0; c < 2; ++c)
        rd_addr[c] = lm * 64 + (((c * 4 + lq) ^ x7) * 8);

    // RoPE inverse-frequency table for this lane's d = lq*8+j (pass-invariant)
    float invt[8];
    for (int j = 0; j < 8; ++j)
        invt[j] = __expf(-(float)(2 * (lq * 8 + j)) * (1.0f / 64.0f) * 9.210340371976184f);

    const int srow = tid >> 3, sch = tid & 7;
    const bf16* kgb = QKV + (long)b * cS * cQKVW + 2048 + kvh * cDH;
    const bf16* vgb = VT + (long)(b * cNKV + kvh) * cDH * cS;
    const int sc8 = (sch ^ (srow & 7)) * 8;    // (32+srow)&7 == srow&7
    const bf16* kp0 = kgb + (long)srow * cQKVW + sc8;
    const bf16* kp1 = kgb + (long)(32 + srow) * cQKVW + sc8;
    const bf16* vp0 = vgb + (long)srow * cS + sc8;
    const bf16* vp1 = vgb + (long)(32 + srow) * cS + sc8;
    auto stage = [&](int buf, int j0) {
        long ko = (long)j0 * cQKVW;
        async_cp16(kp0 + ko, &Kl[buf][tid * 8]);
        async_cp16(kp1 + ko, &Kl[buf][2048 + tid * 8]);
        async_cp16(vp0 + j0, &Vl[buf][tid * 8]);
        async_cp16(vp1 + j0, &Vl[buf][2048 + tid * 8]);
    };

    for (int pass = 0; pass < 2; ++pass) {
        const int qblk = pass ? pair : 15 - pair;   // heavy pass first
        const int q0 = qblk * 128;
        const int qw = q0 + wave * 32;              // this wave's 32 queries
        const int nsteps = 2 * qblk + 2;

        bf8v qf[2][2];
        for (int u = 0; u < 2; ++u) {
            const int qi = qw + u * 16 + lm;
            const bf16* qrow = QKV + (long)(b * cS + qi) * cQKVW + h * cDH;
            float p = (float)pos[b * cS + qi];
            bf8v r0 = *(const bf8v*)(qrow + lq * 8);
            bf8v r1 = *(const bf8v*)(qrow + 32 + lq * 8);
            bf8v t0, t1;
            for (int j = 0; j < 8; ++j) {
                float sn, cs;
                __sincosf(p * invt[j], &sn, &cs);
                float a = (float)r0[j], c2 = (float)r1[j];
                t0[j] = (__bf16)((a * cs - c2 * sn) * SCALE);
                t1[j] = (__bf16)((c2 * cs + a * sn) * SCALE);
            }
            qf[u][0] = t0; qf[u][1] = t1;
        }

        float lrow[2] = {0.f, 0.f};
        f4v o[2][4];
        for (int u = 0; u < 2; ++u)
            for (int t = 0; t < 4; ++t)
                for (int r = 0; r < 4; ++r) o[u][t][r] = 0.f;

        stage(0, 0);
        for (int step = 0; step < nsteps; ++step) {
            const int j0 = step * 64;
            const int cur = step & 1;
            if (step + 1 < nsteps) {
                stage(cur ^ 1, j0 + 64);
                asm volatile("s_waitcnt vmcnt(4)" ::: "memory");  // current tile only
            } else {
                asm volatile("s_waitcnt vmcnt(0)" ::: "memory");
            }
            asm volatile("s_barrier" ::: "memory");

            if (qw + 31 >= j0) {   // wave-uniform; skip fully-masked steps
                f4v st[2][4];
                for (int u = 0; u < 2; ++u)
                    for (int t = 0; t < 4; ++t)
                        for (int r = 0; r < 4; ++r) st[u][t][r] = 0.f;
                __builtin_amdgcn_s_setprio(1);
                for (int t = 0; t < 4; ++t) {
                    int kr = t * 16 + lm;
                    bf8v kf0 = *(const bf8v*)&Kl[cur][kr * 64 + ((lq ^ (kr & 7)) * 8)];
                    bf8v kf1 = *(const bf8v*)&Kl[cur][kr * 64 + (((4 + lq) ^ (kr & 7)) * 8)];
                    for (int u = 0; u < 2; ++u) {
                        st[u][t] = mfma_16x16x32(kf0, qf[u][0], st[u][t]);
                        st[u][t] = mfma_16x16x32(kf1, qf[u][1], st[u][t]);
                    }
                }
                __builtin_amdgcn_s_setprio(0);
                bf8v vf[4][2];
                for (int t = 0; t < 4; ++t) {
                    int vr = t * 16 + lm;
                    vf[t][0] = *(const bf8v*)&Vl[cur][vr * 64 + ((lq ^ (vr & 7)) * 8)];
                    vf[t][1] = *(const bf8v*)&Vl[cur][vr * 64 + (((4 + lq) ^ (vr & 7)) * 8)];
                }
                const bool full = (j0 + 63 <= qw);
                // ---- softmax + pack + write BOTH u (no drain between) ----
                for (int u = 0; u < 2; ++u) {
                    float part = 0.f;
                    if (full) {
                        for (int t = 0; t < 4; ++t)
                            for (int r = 0; r < 4; ++r) {
                                float pv = __builtin_amdgcn_exp2f(st[u][t][r]);
                                st[u][t][r] = pv;
                                part += pv;
                            }
                    } else {
                        const int qi = qw + u * 16 + lm;
                        for (int t = 0; t < 4; ++t)
                            for (int r = 0; r < 4; ++r) {
                                int key = j0 + t * 16 + lq * 4 + r;
                                float pv = (key <= qi)
                                         ? __builtin_amdgcn_exp2f(st[u][t][r]) : 0.f;
                                st[u][t][r] = pv;
                                part += pv;
                            }
                    }
                    lrow[u] += part;
                    bf16* pw = &Pl[wave][u][0];
                    for (int t = 0; t < 4; ++t) {
                        union { bf16 h4[4]; uint2 v; } pk;
                        pk.h4[0] = __float2bfloat16(st[u][t][0]);
                        pk.h4[1] = __float2bfloat16(st[u][t][1]);
                        pk.h4[2] = __float2bfloat16(st[u][t][2]);
                        pk.h4[3] = __float2bfloat16(st[u][t][3]);
                        *(uint2*)&pw[wr_addr[t]] = pk.v;
                    }
                }
                // ---- ONE drain, then read + PV both u ----
                asm volatile("s_waitcnt lgkmcnt(0)" ::: "memory");
                for (int u = 0; u < 2; ++u) {
                    bf16* pw = &Pl[wave][u][0];
                    bf8v pb0 = *(const bf8v*)&pw[rd_addr[0]];
                    bf8v pb1 = *(const bf8v*)&pw[rd_addr[1]];
                    __builtin_amdgcn_s_setprio(1);
                    for (int t = 0; t < 4; ++t) {
                        o[u][t] = mfma_16x16x32(vf[t][0], pb0, o[u][t]);
                        o[u][t] = mfma_16x16x32(vf[t][1], pb1, o[u][t]);
                    }
                    __builtin_amdgcn_s_setprio(0);
                }
            }
            asm volatile("s_barrier" ::: "memory");   // reads done -> next stage may overwrite
        }

        for (int u = 0; u < 2; ++u) {
            lrow[u] += __shfl_xor(lrow[u], 16);
            lrow[u] += __shfl_xor(lrow[u], 32);
            float inv = 1.0f / lrow[u];
            const int qi = qw + u * 16 + lm;
            bf16* orow = O + ((long)(b * cS + qi) * cNH + h) * cDH;
            for (int t = 0; t < 4; ++t) {
                union { bf16 h4[4]; uint2 v; } pk;
                pk.h4[0] = __float2bfloat16(o[u][t][0] * inv);
                pk.h4[1] = __float2bfloat16(o[u][t][1] * inv);
                pk.h4[2] = __float2bfloat16(o[u][t][2] * inv);
                pk.h4[3] = __float2bfloat16(o[u][t][3] * inv);
                *(uint2*)(orow + t * 16 + lq * 4) = pk.v;
            }
        }
    }
}

// ---------------------------------------------------------------------------
// launcher: 4 dispatches
// ---------------------------------------------------------------------------
extern "C" void kernel_launch(void* const* d_in, const int* in_sizes, int n_in,
                              void* d_out, int out_size, void* d_ws, size_t ws_size,
                              hipStream_t stream) {
    const float* hs  = (const float*)d_in[0];
    const int*   pos = (const int*)d_in[1];
    const float* Wq  = (const float*)d_in[2];
    const float* Wk  = (const float*)d_in[3];
    const float* Wv  = (const float*)d_in[4];
    const float* Wo  = (const float*)d_in[5];
    float* out = (float*)d_out;
    char* ws = (char*)d_ws;

    // workspace layout (bytes)
    bf16* hsb = (bf16*)(ws + 0);              // [4096][2048]        16.78 MB
    bf16* WT  = (bf16*)(ws + 16777216);       // [3072][2048] fused QKV^T 12.58 MB
    bf16* WoT = (bf16*)(ws + 29360128);       // [2048][2048]         8.39 MB
    bf16* QKV = (bf16*)(ws + 37748736);       // [4096][3072]        25.17 MB
    bf16* VTb = (bf16*)(ws + 62914560);       // [2][8][64][2048]     4.19 MB
    bf16* AOb = (bf16*)(ws + 67108864);       // [4096][2048]        16.78 MB
    // total 83.9 MB

    // 1) fused prep: hs->bf16 + all weight transposes
    prep_kernel<<<18432, 256, 0, stream>>>(hs, hsb, Wq, Wk, Wv, Wo, WT, WoT);
    // 2) fused QKV projection + K-RoPE + V-transpose (8-phase 256^2, XCD swz)
    gemm_bt8_qkv<<<192, 512, 0, stream>>>(hsb, WT, QKV, pos, VTb,
                                          4096, cQKVW, 2048);
    // 3) attention (512 uniform blocks, paired q-tiles, merged P-drain)
    attn_kernel<<<512, 256, 0, stream>>>(QKV, VTb, pos, AOb);
    // 4) output projection -> fp32 d_out (2-phase 128x256, 256 blocks, XCD swz)
    gemm2_out<<<256, 512, 0, stream>>>(AOb, WoT, out, 4096, 2048, 2048);
}

// Round 11
// 291.292 us; speedup vs baseline: 1.0610x; 1.0460x over previous
//
#include <hip/hip_runtime.h>
#include <hip/hip_bf16.h>

// ---------------------------------------------------------------------------
// OptimizedAttention R14: housekeeping round (GEMM schedules frozen after 4
// rewrites land within +/-2% -- qkv pinned at 2-phase-class 683 TF).
//  1) prep: 64x64 transpose tiles, uint-packed bf16x2 writes (128B segments
//     per 32 lanes, was 64B), 4x fewer tile blocks.
//  2) Wo transpose moved INTO qkv dispatch: blocks 192..255 (CUs idle during
//     the 192-block GEMM) transpose Wo -> WoT, needed only by outproj.
//  3) ws compaction: AOb aliases hsb (dead after qkv). 83.9 -> 67.1 MB.
// qkv = R11 8-phase 256^2 (ledger in comment); outproj = R12 2-phase
// 128x256; attn = R13 (merged P-drain).
// B=2 S=2048 H=2048 NH=32 NKV=8 DH=64 N_REP=4 THETA=1e4
// ---------------------------------------------------------------------------

using bf16 = __hip_bfloat16;
typedef __attribute__((ext_vector_type(8))) __bf16 bf8v;   // MFMA A/B frag (4 VGPR)
typedef __attribute__((ext_vector_type(4))) float  f4v;    // MFMA C/D frag

#define AS1 __attribute__((address_space(1)))
#define AS3 __attribute__((address_space(3)))

constexpr int cB = 2, cS = 2048, cH = 2048, cNH = 32, cNKV = 8, cDH = 64;
constexpr int cQKVW = 3072;   // fused QKV row width (2048 Q + 512 K + 512 V)

template <int N> struct ic { static constexpr int value = N; };

__device__ __forceinline__ void async_cp16(const bf16* g, bf16* l) {
    __builtin_amdgcn_global_load_lds((const AS1 unsigned int*)(const void*)g,
                                     (AS3 unsigned int*)(void*)l, 16, 0, 0);
}

__device__ __forceinline__ f4v mfma_16x16x32(bf8v a, bf8v b, f4v c) {
    return __builtin_amdgcn_mfma_f32_16x16x32_bf16(a, b, c, 0, 0, 0);
}

// ---------------------------------------------------------------------------
// prep: fused hs->bf16 cvt + Wq/Wk/Wv transposes (f32 [2048][C] -> bf16
// [C][2048]). 64x64 tiles, 256 threads; writes packed 2xbf16 -> 128B
// segments per 32 lanes. Wo is transposed inside the qkv dispatch.
// grid: [0,8192) cvt; [8192,9216) Wq; [9216,9472) Wk; [9472,9728) Wv.
// ---------------------------------------------------------------------------
__global__ void prep_kernel(const float* __restrict__ hs, bf16* __restrict__ hsb,
                            const float* __restrict__ Wq, const float* __restrict__ Wk,
                            const float* __restrict__ Wv, bf16* __restrict__ WT) {
    __shared__ float t64[64][65];
    const int bz = blockIdx.x, tid = threadIdx.x;
    if (bz < 8192) {
        int i = bz * 256 + tid;
        float4 v = ((const float4*)hs)[i];
        union { bf16 h[4]; uint2 u; } p;
        p.h[0] = __float2bfloat16(v.x);
        p.h[1] = __float2bfloat16(v.y);
        p.h[2] = __float2bfloat16(v.z);
        p.h[3] = __float2bfloat16(v.w);
        ((uint2*)hsb)[i] = p.u;
        return;
    }
    const int t = bz - 8192;
    const float* in; bf16* outp; int C, x, y;
    if (t < 1024)      { in = Wq; outp = WT;               C = 2048; x = t & 31; y = t >> 5; }
    else if (t < 1280) { int l = t - 1024; in = Wk; outp = WT + 2048 * 2048; C = 512; x = l & 7; y = l >> 3; }
    else               { int l = t - 1280; in = Wv; outp = WT + 2560 * 2048; C = 512; x = l & 7; y = l >> 3; }
    const int c0 = x * 64, r0 = y * 64;
    const int lx = tid & 63;
    for (int k = tid >> 6; k < 64; k += 4)
        t64[k][lx] = in[(long)(r0 + k) * C + c0 + lx];
    __syncthreads();
    const int x2 = (tid & 31) * 2;
    for (int i = tid >> 5; i < 64; i += 8) {
        union { bf16 h[2]; unsigned u; } pk;
        pk.h[0] = __float2bfloat16(t64[x2][i]);
        pk.h[1] = __float2bfloat16(t64[x2 + 1][i]);
        *(unsigned*)&outp[(long)(c0 + i) * 2048 + r0 + x2] = pk.u;
    }
}

// ---------------------------------------------------------------------------
// 256x256-tile 8-phase GEMM core (R6/R11-verified ledger).
// Per K-tile t (4 phases of {ds_read; prefetch-issue; barrier; lgkmcnt(0);
// setprio(1); 16 MFMA; setprio(0); [counted vmcnt]; barrier}):
//   ph0: issue A-u0(t+1)->buf^1   ph1: issue A-u1(t+1)->buf^1, vmcnt(8)
//   ph2: issue B-h0(t+2)->buf     ph3: issue B-h1(t+2)->buf,   vmcnt(6)
// B region of buf is dead after ph0; entry ledger {A-u1(t)[2], B(t+1)[4]}=6.
// Chunk-XOR swizzle c^=(row&7) on global SOURCE + ds_read (conflict-free).
// ---------------------------------------------------------------------------
#define GEMM_CORE(AARG, BTARG, KARG, BXV, BYV)                                  \
    const int tid  = threadIdx.x;                                               \
    const int lane = tid & 63;                                                  \
    const int wave = tid >> 6;                                                  \
    const int wm = wave >> 2, wn = wave & 3;                                    \
    const int lm = lane & 15, lq = lane >> 4;                                   \
    const int bm = (BXV) * 256, bn = (BYV) * 256;                               \
    const int NT = (KARG) >> 6;                                                 \
    f4v acc[8][4];                                                              \
    _Pragma("unroll")                                                           \
    for (int i = 0; i < 8; ++i)                                                 \
        _Pragma("unroll")                                                       \
        for (int j = 0; j < 4; ++j)                                             \
            for (int r = 0; r < 4; ++r) acc[i][j][r] = 0.f;                     \
    const bf16* aP[2][2]; const bf16* bP[2][2];                                 \
    int aD[2][2], bD[2][2];                                                     \
    _Pragma("unroll")                                                           \
    for (int u = 0; u < 2; ++u)                                                 \
        _Pragma("unroll")                                                       \
        for (int i = 0; i < 2; ++i) {                                           \
            int g = tid + i * 512;                                              \
            int ur = g >> 3, dc = g & 7;                                        \
            int row = ur + (ur & 64) + u * 64;                                  \
            int gch = dc ^ (row & 7);                                           \
            aP[u][i] = (AARG) + (long)(bm + row) * (KARG) + gch * 8;            \
            aD[u][i] = row * 64 + dc * 8;                                       \
        }                                                                       \
    _Pragma("unroll")                                                           \
    for (int h = 0; h < 2; ++h)                                                 \
        _Pragma("unroll")                                                       \
        for (int i = 0; i < 2; ++i) {                                           \
            int g = tid + i * 512;                                              \
            int ur = g >> 3, dc = g & 7;                                        \
            int row = h * 128 + ur;                                             \
            int gch = dc ^ (row & 7);                                           \
            bP[h][i] = (BTARG) + (long)(bn + row) * (KARG) + gch * 8;           \
            bD[h][i] = row * 64 + dc * 8;                                       \
        }                                                                       \
    auto stageA = [&](int buf, int t, int u) {                                  \
        long ko = (long)t * 64;                                                 \
        async_cp16(aP[u][0] + ko, &Al[buf][aD[u][0]]);                          \
        async_cp16(aP[u][1] + ko, &Al[buf][aD[u][1]]);                          \
    };                                                                          \
    auto stageB = [&](int buf, int t, int h) {                                  \
        long ko = (long)t * 64;                                                 \
        async_cp16(bP[h][0] + ko, &Bl[buf][bD[h][0]]);                          \
        async_cp16(bP[h][1] + ko, &Bl[buf][bD[h][1]]);                          \
    };                                                                          \
    const int x7 = lm & 7;                                                      \
    const int co0 = (lq ^ x7) * 8;                                              \
    const int co1 = ((4 + lq) ^ x7) * 8;                                        \
    const int abase = (wm * 128 + lm) * 64;                                     \
    const int bbase = (wn * 64 + lm) * 64;                                      \
    stageB(0, 0, 0); stageB(0, 0, 1); stageA(0, 0, 0); stageA(0, 0, 1);         \
    stageB(1, 1, 0); stageB(1, 1, 1);                                           \
    asm volatile("s_waitcnt vmcnt(6)" ::: "memory");                            \
    asm volatile("s_barrier" ::: "memory");                                     \
    auto ktile = [&](int t, bool ia, bool ib, auto w1, auto w3) {               \
        const int cb = t & 1;                                                   \
        const bf16* Ac = &Al[cb][0];                                            \
        const bf16* Bc = &Bl[cb][0];                                            \
        bf8v bfr[4][2];                                                         \
        _Pragma("unroll")                                                       \
        for (int q = 0; q < 4; ++q) {                                           \
            bf8v afr[2][2];                                                     \
            if (q == 0) {                                                       \
                _Pragma("unroll")                                               \
                for (int n = 0; n < 4; ++n) {                                   \
                    bfr[n][0] = *(const bf8v*)&Bc[bbase + n * 1024 + co0];      \
                    bfr[n][1] = *(const bf8v*)&Bc[bbase + n * 1024 + co1];      \
                }                                                               \
            }                                                                   \
            _Pragma("unroll")                                                   \
            for (int i2 = 0; i2 < 2; ++i2) {                                    \
                afr[i2][0] = *(const bf8v*)&Ac[abase + (q * 2 + i2) * 1024 + co0]; \
                afr[i2][1] = *(const bf8v*)&Ac[abase + (q * 2 + i2) * 1024 + co1]; \
            }                                                                   \
            if (q == 0 && ia) stageA(cb ^ 1, t + 1, 0);                         \
            if (q == 1 && ia) stageA(cb ^ 1, t + 1, 1);                         \
            if (q == 2 && ib) stageB(cb, t + 2, 0);                             \
            if (q == 3 && ib) stageB(cb, t + 2, 1);                             \
            asm volatile("s_barrier" ::: "memory");                             \
            asm volatile("s_waitcnt lgkmcnt(0)" ::: "memory");                  \
            __builtin_amdgcn_s_setprio(1);                                      \
            _Pragma("unroll")                                                   \
            for (int i2 = 0; i2 < 2; ++i2)                                      \
                _Pragma("unroll")                                               \
                for (int n = 0; n < 4; ++n) {                                   \
                    acc[q * 2 + i2][n] = mfma_16x16x32(afr[i2][0], bfr[n][0], acc[q * 2 + i2][n]); \
                    acc[q * 2 + i2][n] = mfma_16x16x32(afr[i2][1], bfr[n][1], acc[q * 2 + i2][n]); \
                }                                                               \
            __builtin_amdgcn_s_setprio(0);                                      \
            if (q == 1) {                                                       \
                if constexpr (decltype(w1)::value == 8)                         \
                    asm volatile("s_waitcnt vmcnt(8)" ::: "memory");            \
                else                                                            \
                    asm volatile("s_waitcnt vmcnt(0)" ::: "memory");            \
            }                                                                   \
            if (q == 3) {                                                       \
                if constexpr (decltype(w3)::value == 1)                         \
                    asm volatile("s_waitcnt vmcnt(6)" ::: "memory");            \
                else if constexpr (decltype(w3)::value == 2)                    \
                    asm volatile("s_waitcnt vmcnt(2)" ::: "memory");            \
            }                                                                   \
            asm volatile("s_barrier" ::: "memory");                             \
        }                                                                       \
    };                                                                          \
    {                                                                           \
        int t = 0;                                                              \
        for (; t + 2 < NT; ++t) ktile(t, true, true, ic<8>{}, ic<1>{});         \
        ktile(t, true, false, ic<8>{}, ic<2>{});                                \
        ++t;                                                                    \
        ktile(t, false, false, ic<0>{}, ic<0>{});                               \
    }

// QKV variant (R11 schedule): grid 256; blocks 0..191 = GEMM (XCD-chunked
// swizzle), blocks 192..255 = Wo transpose on otherwise-idle CUs (WoT is
// needed only by the outproj dispatch, 2 launches later).
// byv 0..7 = Q, 8..9 = K (fused RoPE; pairs (d,d+32) lane-local
// acc[mi][n]<->acc[mi][n+2]), 10..11 = V (transposed store to VT).
__global__ __launch_bounds__(512)
void gemm_bt8_qkv(const bf16* __restrict__ A, const bf16* __restrict__ BT,
                  bf16* __restrict__ C, const int* __restrict__ pos,
                  bf16* __restrict__ VTout,
                  const float* __restrict__ Wo, bf16* __restrict__ WoT,
                  int M, int N, int K) {
    __shared__ __align__(16) bf16 Al[2][256 * 64];   // 32 KB x2
    __shared__ __align__(16) bf16 Bl[2][256 * 64];   // 32 KB x2
    const int bid = blockIdx.x;
    if (bid >= 192) {
        // ---- Wo transpose rider: 64 blocks x 16 tiles of 64x64 ----
        float (*t64)[65] = (float (*)[65])&Al[0][0];   // 16.6 KB, reuse LDS
        const int tid2 = threadIdx.x;
        const int unit = bid - 192;
        const int lx = tid2 & 63;
        const int x2 = (tid2 & 31) * 2;
        for (int s = 0; s < 16; ++s) {
            int l = unit * 16 + s;                 // 0..1023
            int x = l & 31, y = l >> 5;
            int c0 = x * 64, r0 = y * 64;
            for (int k = tid2 >> 6; k < 64; k += 8)
                t64[k][lx] = Wo[(long)(r0 + k) * 2048 + c0 + lx];
            __syncthreads();
            for (int i = tid2 >> 5; i < 64; i += 16) {
                union { bf16 h[2]; unsigned u; } pk;
                pk.h[0] = __float2bfloat16(t64[x2][i]);
                pk.h[1] = __float2bfloat16(t64[x2 + 1][i]);
                *(unsigned*)&WoT[(long)(c0 + i) * 2048 + r0 + x2] = pk.u;
            }
            __syncthreads();
        }
        return;
    }
    const int lin = (bid & 7) * 24 + (bid >> 3);
    const int bxv = lin / 12, byv = lin % 12;
    GEMM_CORE(A, BT, K, bxv, byv)
    if (byv < 8) {
        #pragma unroll
        for (int mi = 0; mi < 8; ++mi) {
            int row = bm + wm * 128 + mi * 16 + lq * 4;
            #pragma unroll
            for (int n = 0; n < 4; ++n) {
                int col = bn + wn * 64 + n * 16 + lm;
                for (int r = 0; r < 4; ++r)
                    C[(long)(row + r) * N + col] = __float2bfloat16(acc[mi][n][r]);
            }
        }
    } else if (byv < 10) {
        #pragma unroll
        for (int mi = 0; mi < 8; ++mi) {
            int row = bm + wm * 128 + mi * 16 + lq * 4;
            float pr[4];
            for (int r = 0; r < 4; ++r) pr[r] = (float)pos[row + r];
            #pragma unroll
            for (int n = 0; n < 2; ++n) {
                int d = n * 16 + lm;
                float inv = __expf(-(float)(2 * d) * (1.0f / 64.0f) * 9.210340371976184f);
                int col = bn + wn * 64 + n * 16 + lm;
                for (int r = 0; r < 4; ++r) {
                    float a  = acc[mi][n][r];
                    float c2 = acc[mi][n + 2][r];
                    float sn, cs;
                    __sincosf(pr[r] * inv, &sn, &cs);
                    C[(long)(row + r) * N + col]      = __float2bfloat16(a * cs - c2 * sn);
                    C[(long)(row + r) * N + col + 32] = __float2bfloat16(c2 * cs + a * sn);
                }
            }
        }
    } else {
        #pragma unroll
        for (int mi = 0; mi < 8; ++mi) {
            int row = bm + wm * 128 + mi * 16 + lq * 4;
            int b = row >> 11, tok = row & 2047;
            #pragma unroll
            for (int n = 0; n < 4; ++n) {
                int vc = bn + wn * 64 + n * 16 + lm - 2560;
                int kv = vc >> 6, d = vc & 63;
                union { bf16 h4[4]; uint2 v; } pk;
                pk.h4[0] = __float2bfloat16(acc[mi][n][0]);
                pk.h4[1] = __float2bfloat16(acc[mi][n][1]);
                pk.h4[2] = __float2bfloat16(acc[mi][n][2]);
                pk.h4[3] = __float2bfloat16(acc[mi][n][3]);
                *(uint2*)&VTout[((long)(b * 8 + kv) * 64 + d) * 2048 + tok] = pk.v;
            }
        }
    }
}

// ---------------------------------------------------------------------------
// Outproj GEMM (R12 exact): 128x256 tile, 2 phases/K-tile (16 MFMA each),
// 8 waves (2M x 4N, wave tile 64x64, acc[4][4]). Grid 256 = all CUs, XCD-
// chunked. Ledger: entry {B(t+1)[4]}; ph0 issues A(t+1)[2]; ph1 issues
// B(t+2)[4] into live buf's dead B region; vmcnt(4) lands B(t+1)+A(t+1).
// ---------------------------------------------------------------------------
__global__ __launch_bounds__(512)
void gemm2_out(const bf16* __restrict__ A, const bf16* __restrict__ BT,
               float* __restrict__ C, int M, int N, int K) {
    __shared__ __align__(16) bf16 Al[2][128 * 64];   // 16 KB x2
    __shared__ __align__(16) bf16 Bl[2][256 * 64];   // 32 KB x2
    const int tid  = threadIdx.x;
    const int lane = tid & 63, wave = tid >> 6;
    const int wm = wave >> 2, wn = wave & 3;
    const int lm = lane & 15, lq = lane >> 4;
    const int bid = blockIdx.x;
    const int lin = (bid & 7) * 32 + (bid >> 3);
    const int bm = (lin >> 3) * 128, bn = (lin & 7) * 256;
    const int NT = K >> 6;

    f4v acc[4][4];
    #pragma unroll
    for (int i = 0; i < 4; ++i)
        #pragma unroll
        for (int j = 0; j < 4; ++j)
            for (int r = 0; r < 4; ++r) acc[i][j][r] = 0.f;

    const bf16* aP[2]; int aD[2];
    #pragma unroll
    for (int i = 0; i < 2; ++i) {
        int g = tid + i * 512;
        int ur = g >> 3, dc = g & 7;
        int gch = dc ^ (ur & 7);
        aP[i] = A + (long)(bm + ur) * K + gch * 8;
        aD[i] = ur * 64 + dc * 8;
    }
    const bf16* bP[4]; int bD[4];
    #pragma unroll
    for (int i = 0; i < 4; ++i) {
        int g = tid + i * 512;
        int ur = g >> 3, dc = g & 7;
        int gch = dc ^ (ur & 7);
        bP[i] = BT + (long)(bn + ur) * K + gch * 8;
        bD[i] = ur * 64 + dc * 8;
    }
    auto stageA = [&](int buf, int t) {
        long ko = (long)t * 64;
        #pragma unroll
        for (int i = 0; i < 2; ++i) async_cp16(aP[i] + ko, &Al[buf][aD[i]]);
    };
    auto stageB = [&](int buf, int t) {
        long ko = (long)t * 64;
        #pragma unroll
        for (int i = 0; i < 4; ++i) async_cp16(bP[i] + ko, &Bl[buf][bD[i]]);
    };

    const int x7 = lm & 7;
    const int co0 = (lq ^ x7) * 8;
    const int co1 = ((4 + lq) ^ x7) * 8;
    const int abase = (wm * 64 + lm) * 64;
    const int bbase = (wn * 64 + lm) * 64;

    stageB(0, 0); stageA(0, 0); stageB(1, 1);
    asm volatile("s_waitcnt vmcnt(4)" ::: "memory");
    asm volatile("s_barrier" ::: "memory");

    auto ktile = [&](int t, bool ia, bool ib, auto w) {
        const int cb = t & 1;
        const bf16* Ac = &Al[cb][0];
        const bf16* Bc = &Bl[cb][0];
        bf8v bfr[4][2], afr[2][2];
        #pragma unroll
        for (int n = 0; n < 4; ++n) {
            bfr[n][0] = *(const bf8v*)&Bc[bbase + n * 1024 + co0];
            bfr[n][1] = *(const bf8v*)&Bc[bbase + n * 1024 + co1];
        }
        #pragma unroll
        for (int mi = 0; mi < 2; ++mi) {
            afr[mi][0] = *(const bf8v*)&Ac[abase + mi * 1024 + co0];
            afr[mi][1] = *(const bf8v*)&Ac[abase + mi * 1024 + co1];
        }
        if (ia) stageA(cb ^ 1, t + 1);
        asm volatile("s_barrier" ::: "memory");
        asm volatile("s_waitcnt lgkmcnt(0)" ::: "memory");
        __builtin_amdgcn_s_setprio(1);
        #pragma unroll
        for (int mi = 0; mi < 2; ++mi)
            #pragma unroll
            for (int n = 0; n < 4; ++n) {
                acc[mi][n] = mfma_16x16x32(afr[mi][0], bfr[n][0], acc[mi][n]);
                acc[mi][n] = mfma_16x16x32(afr[mi][1], bfr[n][1], acc[mi][n]);
            }
        __builtin_amdgcn_s_setprio(0);
        asm volatile("s_barrier" ::: "memory");
        #pragma unroll
        for (int mi = 0; mi < 2; ++mi) {
            afr[mi][0] = *(const bf8v*)&Ac[abase + (2 + mi) * 1024 + co0];
            afr[mi][1] = *(const bf8v*)&Ac[abase + (2 + mi) * 1024 + co1];
        }
        if (ib) stageB(cb, t + 2);   // dead B region of live buffer
        asm volatile("s_barrier" ::: "memory");
        asm volatile("s_waitcnt lgkmcnt(0)" ::: "memory");
        __builtin_amdgcn_s_setprio(1);
        #pragma unroll
        for (int mi = 0; mi < 2; ++mi)
            #pragma unroll
            for (int n = 0; n < 4; ++n) {
                acc[2 + mi][n] = mfma_16x16x32(afr[mi][0], bfr[n][0], acc[2 + mi][n]);
                acc[2 + mi][n] = mfma_16x16x32(afr[mi][1], bfr[n][1], acc[2 + mi][n]);
            }
        __builtin_amdgcn_s_setprio(0);
        if constexpr (decltype(w)::value == 4)
            asm volatile("s_waitcnt vmcnt(4)" ::: "memory");
        else if constexpr (decltype(w)::value == 0)
            asm volatile("s_waitcnt vmcnt(0)" ::: "memory");
        asm volatile("s_barrier" ::: "memory");
    };

    int t = 0;
    for (; t + 2 < NT; ++t) ktile(t, true, true, ic<4>{});
    ktile(t, true, false, ic<0>{});
    ++t;
    ktile(t, false, false, ic<9>{});

    #pragma unroll
    for (int mi = 0; mi < 4; ++mi) {
        int row = bm + wm * 64 + mi * 16 + lq * 4;
        #pragma unroll
        for (int n = 0; n < 4; ++n) {
            int col = bn + wn * 64 + n * 16 + lm;
            for (int r = 0; r < 4; ++r)
                C[(long)(row + r) * N + col] = acc[mi][n][r];
        }
    }
}

// ---------------------------------------------------------------------------
// Causal GQA flash attention (R13 exact). 512 blocks; paired q-tiles
// (15-p, p) = uniform 34 steps; 4 waves x 32q; XOR-swizzled async K/VT
// staging, dbuf, s_barrier+vmcnt(4); fixed-base exp2 softmax; Q-RoPE fused
// (inv-freq hoisted); merged P-drain (per-u P buffers, one lgkmcnt(0));
// setprio around MFMA. XCD affinity: idx&7 = kvh.
// ---------------------------------------------------------------------------
__global__ __launch_bounds__(256)
void attn_kernel(const bf16* __restrict__ QKV, const bf16* __restrict__ VT,
                 const int* __restrict__ pos, bf16* __restrict__ O) {
    __shared__ __align__(16) bf16 Kl[2][64 * 64];      // [buf][key][dh]  8KB x2
    __shared__ __align__(16) bf16 Vl[2][64 * 64];      // [buf][d][key]   8KB x2
    __shared__ __align__(16) bf16 Pl[4][2][16 * 64];   // per-wave, per-u
    const int tid  = threadIdx.x;
    const int wave = tid >> 6, lane = tid & 63;
    const int lm = lane & 15, lq = lane >> 4;
    const int idx = blockIdx.x;
    const int pair = idx >> 6;                      // 0..7
    const int bh2 = idx & 15;
    const int rep = (idx >> 4) & 3;
    const int b = bh2 >> 3, kvh = bh2 & 7;
    const int h = kvh * 4 + rep;

    constexpr float SCALE = 0.18033688011112042f;

    const int x7 = lm & 7;
    int wr_addr[4], rd_addr[2];
    for (int t = 0; t < 4; ++t)
        wr_addr[t] = lm * 64 + (((t * 2 + (lq >> 1)) ^ x7) * 8) + (lq & 1) * 4;
    for (int c = 0; c < 2; ++c)
        rd_addr[c] = lm * 64 + (((c * 4 + lq) ^ x7) * 8);

    float invt[8];
    for (int j = 0; j < 8; ++j)
        invt[j] = __expf(-(float)(2 * (lq * 8 + j)) * (1.0f / 64.0f) * 9.210340371976184f);

    const int srow = tid >> 3, sch = tid & 7;
    const bf16* kgb = QKV + (long)b * cS * cQKVW + 2048 + kvh * cDH;
    const bf16* vgb = VT + (long)(b * cNKV + kvh) * cDH * cS;
    const int sc8 = (sch ^ (srow & 7)) * 8;    // (32+srow)&7 == srow&7
    const bf16* kp0 = kgb + (long)srow * cQKVW + sc8;
    const bf16* kp1 = kgb + (long)(32 + srow) * cQKVW + sc8;
    const bf16* vp0 = vgb + (long)srow * cS + sc8;
    const bf16* vp1 = vgb + (long)(32 + srow) * cS + sc8;
    auto stage = [&](int buf, int j0) {
        long ko = (long)j0 * cQKVW;
        async_cp16(kp0 + ko, &Kl[buf][tid * 8]);
        async_cp16(kp1 + ko, &Kl[buf][2048 + tid * 8]);
        async_cp16(vp0 + j0, &Vl[buf][tid * 8]);
        async_cp16(vp1 + j0, &Vl[buf][2048 + tid * 8]);
    };

    for (int pass = 0; pass < 2; ++pass) {
        const int qblk = pass ? pair : 15 - pair;   // heavy pass first
        const int q0 = qblk * 128;
        const int qw = q0 + wave * 32;              // this wave's 32 queries
        const int nsteps = 2 * qblk + 2;

        bf8v qf[2][2];
        for (int u = 0; u < 2; ++u) {
            const int qi = qw + u * 16 + lm;
            const bf16* qrow = QKV + (long)(b * cS + qi) * cQKVW + h * cDH;
            float p = (float)pos[b * cS + qi];
            bf8v r0 = *(const bf8v*)(qrow + lq * 8);
            bf8v r1 = *(const bf8v*)(qrow + 32 + lq * 8);
            bf8v t0, t1;
            for (int j = 0; j < 8; ++j) {
                float sn, cs;
                __sincosf(p * invt[j], &sn, &cs);
                float a = (float)r0[j], c2 = (float)r1[j];
                t0[j] = (__bf16)((a * cs - c2 * sn) * SCALE);
                t1[j] = (__bf16)((c2 * cs + a * sn) * SCALE);
            }
            qf[u][0] = t0; qf[u][1] = t1;
        }

        float lrow[2] = {0.f, 0.f};
        f4v o[2][4];
        for (int u = 0; u < 2; ++u)
            for (int t = 0; t < 4; ++t)
                for (int r = 0; r < 4; ++r) o[u][t][r] = 0.f;

        stage(0, 0);
        for (int step = 0; step < nsteps; ++step) {
            const int j0 = step * 64;
            const int cur = step & 1;
            if (step + 1 < nsteps) {
                stage(cur ^ 1, j0 + 64);
                asm volatile("s_waitcnt vmcnt(4)" ::: "memory");  // current tile only
            } else {
                asm volatile("s_waitcnt vmcnt(0)" ::: "memory");
            }
            asm volatile("s_barrier" ::: "memory");

            if (qw + 31 >= j0) {   // wave-uniform; skip fully-masked steps
                f4v st[2][4];
                for (int u = 0; u < 2; ++u)
                    for (int t = 0; t < 4; ++t)
                        for (int r = 0; r < 4; ++r) st[u][t][r] = 0.f;
                __builtin_amdgcn_s_setprio(1);
                for (int t = 0; t < 4; ++t) {
                    int kr = t * 16 + lm;
                    bf8v kf0 = *(const bf8v*)&Kl[cur][kr * 64 + ((lq ^ (kr & 7)) * 8)];
                    bf8v kf1 = *(const bf8v*)&Kl[cur][kr * 64 + (((4 + lq) ^ (kr & 7)) * 8)];
                    for (int u = 0; u < 2; ++u) {
                        st[u][t] = mfma_16x16x32(kf0, qf[u][0], st[u][t]);
                        st[u][t] = mfma_16x16x32(kf1, qf[u][1], st[u][t]);
                    }
                }
                __builtin_amdgcn_s_setprio(0);
                bf8v vf[4][2];
                for (int t = 0; t < 4; ++t) {
                    int vr = t * 16 + lm;
                    vf[t][0] = *(const bf8v*)&Vl[cur][vr * 64 + ((lq ^ (vr & 7)) * 8)];
                    vf[t][1] = *(const bf8v*)&Vl[cur][vr * 64 + (((4 + lq) ^ (vr & 7)) * 8)];
                }
                const bool full = (j0 + 63 <= qw);
                for (int u = 0; u < 2; ++u) {
                    float part = 0.f;
                    if (full) {
                        for (int t = 0; t < 4; ++t)
                            for (int r = 0; r < 4; ++r) {
                                float pv = __builtin_amdgcn_exp2f(st[u][t][r]);
                                st[u][t][r] = pv;
                                part += pv;
                            }
                    } else {
                        const int qi = qw + u * 16 + lm;
                        for (int t = 0; t < 4; ++t)
                            for (int r = 0; r < 4; ++r) {
                                int key = j0 + t * 16 + lq * 4 + r;
                                float pv = (key <= qi)
                                         ? __builtin_amdgcn_exp2f(st[u][t][r]) : 0.f;
                                st[u][t][r] = pv;
                                part += pv;
                            }
                    }
                    lrow[u] += part;
                    bf16* pw = &Pl[wave][u][0];
                    for (int t = 0; t < 4; ++t) {
                        union { bf16 h4[4]; uint2 v; } pk;
                        pk.h4[0] = __float2bfloat16(st[u][t][0]);
                        pk.h4[1] = __float2bfloat16(st[u][t][1]);
                        pk.h4[2] = __float2bfloat16(st[u][t][2]);
                        pk.h4[3] = __float2bfloat16(st[u][t][3]);
                        *(uint2*)&pw[wr_addr[t]] = pk.v;
                    }
                }
                asm volatile("s_waitcnt lgkmcnt(0)" ::: "memory");
                for (int u = 0; u < 2; ++u) {
                    bf16* pw = &Pl[wave][u][0];
                    bf8v pb0 = *(const bf8v*)&pw[rd_addr[0]];
                    bf8v pb1 = *(const bf8v*)&pw[rd_addr[1]];
                    __builtin_amdgcn_s_setprio(1);
                    for (int t = 0; t < 4; ++t) {
                        o[u][t] = mfma_16x16x32(vf[t][0], pb0, o[u][t]);
                        o[u][t] = mfma_16x16x32(vf[t][1], pb1, o[u][t]);
                    }
                    __builtin_amdgcn_s_setprio(0);
                }
            }
            asm volatile("s_barrier" ::: "memory");   // reads done -> next stage may overwrite
        }

        for (int u = 0; u < 2; ++u) {
            lrow[u] += __shfl_xor(lrow[u], 16);
            lrow[u] += __shfl_xor(lrow[u], 32);
            float inv = 1.0f / lrow[u];
            const int qi = qw + u * 16 + lm;
            bf16* orow = O + ((long)(b * cS + qi) * cNH + h) * cDH;
            for (int t = 0; t < 4; ++t) {
                union { bf16 h4[4]; uint2 v; } pk;
                pk.h4[0] = __float2bfloat16(o[u][t][0] * inv);
                pk.h4[1] = __float2bfloat16(o[u][t][1] * inv);
                pk.h4[2] = __float2bfloat16(o[u][t][2] * inv);
                pk.h4[3] = __float2bfloat16(o[u][t][3] * inv);
                *(uint2*)(orow + t * 16 + lq * 4) = pk.v;
            }
        }
    }
}

// ---------------------------------------------------------------------------
// launcher: 4 dispatches
// ---------------------------------------------------------------------------
extern "C" void kernel_launch(void* const* d_in, const int* in_sizes, int n_in,
                              void* d_out, int out_size, void* d_ws, size_t ws_size,
                              hipStream_t stream) {
    const float* hs  = (const float*)d_in[0];
    const int*   pos = (const int*)d_in[1];
    const float* Wq  = (const float*)d_in[2];
    const float* Wk  = (const float*)d_in[3];
    const float* Wv  = (const float*)d_in[4];
    const float* Wo  = (const float*)d_in[5];
    float* out = (float*)d_out;
    char* ws = (char*)d_ws;

    // workspace layout (bytes) -- AOb aliases hsb (dead after qkv)
    bf16* hsb = (bf16*)(ws + 0);              // [4096][2048]        16.78 MB
    bf16* AOb = (bf16*)(ws + 0);              // attn out, aliases hsb
    bf16* WT  = (bf16*)(ws + 16777216);       // [3072][2048] fused QKV^T 12.58 MB
    bf16* WoT = (bf16*)(ws + 29360128);       // [2048][2048]         8.39 MB
    bf16* QKV = (bf16*)(ws + 37748736);       // [4096][3072]        25.17 MB
    bf16* VTb = (bf16*)(ws + 62914560);       // [2][8][64][2048]     4.19 MB
    // total 67.1 MB

    // 1) fused prep: hs->bf16 + Wq/Wk/Wv transposes (Wo rides with qkv)
    prep_kernel<<<9728, 256, 0, stream>>>(hs, hsb, Wq, Wk, Wv, WT);
    // 2) fused QKV projection + K-RoPE + V-transpose; blocks 192..255
    //    transpose Wo on otherwise-idle CUs (8-phase 256^2, XCD swz)
    gemm_bt8_qkv<<<256, 512, 0, stream>>>(hsb, WT, QKV, pos, VTb, Wo, WoT,
                                          4096, cQKVW, 2048);
    // 3) attention (512 uniform blocks, paired q-tiles, merged P-drain)
    attn_kernel<<<512, 256, 0, stream>>>(QKV, VTb, pos, AOb);
    // 4) output projection -> fp32 d_out (2-phase 128x256, 256 blocks, XCD swz)
    gemm2_out<<<256, 512, 0, stream>>>(AOb, WoT, out, 4096, 2048, 2048);
}